// Round 5
// baseline (357.043 us; speedup 1.0000x reference)
//
#include <hip/hip_runtime.h>
#include <cfloat>

#define N_Q     65536
#define D_DIM   256
#define K_CODES 1024
#define DELTA   0.004f
#define MARGIN  0.001f
#define SW_CAP  1536
#define SPILL_CAP 65536

// output float offsets (tuple concatenated flat, all as float32)
#define OUT_QST   0
#define OUT_LOSS  16777216
#define OUT_IDX   16777217
#define OUT_EMBED 16842753
#define OUT_COUNT 17104897
#define OUT_EMAW  17105921

// workspace byte offsets
#define WS_IDX    0u         // 65536*4: spill pool during sweep, idx after
#define WS_ZZ     262144u    // 65536*4 float ||z||^2 (written by sweep prologue)
#define WS_PERM   524288u    // 65536*4 int CSR permutation
#define WS_PACK   786432u    // 65536*8 uint64 packed (dist,idx), init by prep
#define WS_EN     1310720u   // 1024*4 float ||e||^2
#define WS_ICNT   1314816u   // 1024*4 int counts, zeroed by prep
#define WS_OFFS   1318912u   // 1024*4 int CSR offsets
#define WS_OFFW   1323008u   // 1024*4 int CSR fill cursor
#define WS_CNTF   1327104u   // 1024*4 float counts
#define WS_CS     1331200u   // 1024*4 float laplace-smoothed counts
#define WS_ET     1335296u   // 1024*256*2 bf16 embed in B-fragment layout
#define WS_LOSSB  1859584u   // 1024*8 double loss buckets, zeroed by prep
#define WS_SPCNT  1867776u   // 4 B spill counter, zeroed by prep

typedef short          bf16x8 __attribute__((ext_vector_type(8)));
typedef unsigned short u16x8  __attribute__((ext_vector_type(8)));
typedef float          f32x4  __attribute__((ext_vector_type(4)));

__device__ inline unsigned short f2bf(float x) {   // RNE fp32 -> bf16
    unsigned u = __float_as_uint(x);
    u += 0x7FFFu + ((u >> 16) & 1u);
    return (unsigned short)(u >> 16);
}
__device__ inline float bf2f(unsigned short h) {
    return __uint_as_float((unsigned)h << 16);
}
__device__ inline u16x8 pack8(float4 a, float4 b) {
    u16x8 p;
    p[0]=f2bf(a.x); p[1]=f2bf(a.y); p[2]=f2bf(a.z); p[3]=f2bf(a.w);
    p[4]=f2bf(b.x); p[5]=f2bf(b.y); p[6]=f2bf(b.z); p[7]=f2bf(b.w);
    return p;
}
// async global->LDS, 16B per lane; lds dest is wave-uniform base + lane*16
__device__ inline void gll16(const void* g, void* l) {
    __builtin_amdgcn_global_load_lds(
        (const __attribute__((address_space(1))) unsigned int*)g,
        (__attribute__((address_space(3))) unsigned int*)l, 16, 0, 0);
}
// min with the lane xor-partner via ds_swizzle BitMode (1 instr, no addr math)
#define SWZMIN(x, PAT) fminf((x), __int_as_float( \
    __builtin_amdgcn_ds_swizzle(__float_as_int(x), (PAT))))

// ---------------------------------------------------------------------------
// fused prep: conv_e + pack init (blocks 0..127), ||e||^2 + counter zeroing
// (blocks 128..159).
__global__ void prep_kernel(const float* __restrict__ embed,
                            unsigned short* __restrict__ et,
                            unsigned long long* __restrict__ pack,
                            float* __restrict__ enorm,
                            int* __restrict__ icnt,
                            double* __restrict__ lossb,
                            int* __restrict__ spc)
{
    int b = blockIdx.x, t = threadIdx.x;
    if (b < 128) {
        int tid = b * 256 + t;                        // 32768 threads
        // embed fp32 -> bf16 in MFMA B-fragment layout:
        //   et[((k16*32 + d8)*16 + col)*8 + j] = bf16(e[k16*16+col][d8*8+j])
        int k16 = tid >> 9, d8 = (tid >> 4) & 31, col = tid & 15;
        const float* src = &embed[(size_t)(k16 * 16 + col) * D_DIM + d8 * 8];
        float4 a = *(const float4*)&src[0];
        float4 c = *(const float4*)&src[4];
        *(u16x8*)&et[(size_t)tid * 8] = pack8(a, c);
        // pack init (0xFF..): 16 B per thread covers 65536*8 B
        unsigned long long* p = pack + (size_t)tid * 2;
        p[0] = ~0ull; p[1] = ~0ull;
    } else {
        int b2 = b - 128;                             // 0..31
        int wave = t >> 6, lane = t & 63;
        int rbase = (b2 * 4 + wave) * 8;              // 8 rows per wave
        for (int i = 0; i < 8; ++i) {
            int r = rbase + i;
            const float4 v = *(const float4*)&embed[(size_t)r * D_DIM + lane * 4];
            float s = v.x * v.x + v.y * v.y + v.z * v.z + v.w * v.w;
            #pragma unroll
            for (int m = 32; m >= 1; m >>= 1) s += __shfl_down(s, m, 64);
            if (lane == 0) enorm[r] = s;
        }
        if (b2 == 0) {
            #pragma unroll
            for (int i = 0; i < 4; ++i) {
                icnt[t * 4 + i] = 0;
                lossb[t * 4 + i] = 0.0;
            }
            if (t == 0) *spc = 0;
        }
    }
}

// ---------------------------------------------------------------------------
// MFMA sweep with T=2 B-reuse + codebook half-split:
//   - grid 512 blocks x 512 threads. Block b: queries [(b&255)*256, +256),
//     codes [(b>>8)*512, +512) (8 chunks of 64). Blocks b and b+256 share
//     queries and land on the same XCD under %8 round-robin -> the duplicated
//     z read for A-fragments is L2/L3-absorbed.
//   - each wave owns 32 queries = TWO 16x16 A-tiles; each B fragment read
//     from LDS feeds 2 MFMAs (halves the ds_read instruction count per CU,
//     which round-4 counters showed to be the tallest pole).
//   - per chunk: issue next chunk's 32 KB staging (4 gll16/wave, dbuf),
//     32 ds_read_b128 + 64 MFMA per wave, per-rt epilogue (batched swizzle
//     16-lane min reduce, running-half-min threshold, compact push), then
//     vmcnt(0)+s_barrier (sound: staged loads have a full chunk of compute
//     slack, drain retires free; r3/r4 showed the drain was never the cost).
//   - correctness: per-half running-min threshold pushes a superset of the
//     half's (half_min+DELTA) set; winner's half always pushes the argmin;
//     tail re-filters vs FINAL half-min+DELTA+MARGIN, exact double rescore,
//     ref op order fl(fl(zz-2dot)+en); packed u64 atomicMin merges halves
//     with first-index ties.
// Layouts (verified, guide §3): A[m=lane&15][k=quad*8+j]; C/D col=lane&15,
// row=quad*4+reg. B loaded from E rows (B^T convention, m91).
__launch_bounds__(512, 4)
__global__ void sweep_kernel(const float* __restrict__ z,
                             const float* __restrict__ embed,
                             const unsigned short* __restrict__ et,
                             const float* __restrict__ enorm,
                             float* __restrict__ zzg,
                             unsigned long long* __restrict__ pack,
                             unsigned* __restrict__ spill,
                             int* __restrict__ spc)
{
    __shared__ unsigned short Eb[2][16384];    // 2 x 32 KB E chunk double buffer
    __shared__ unsigned list[SW_CAP];          // 6144 B candidate entries
    __shared__ unsigned short s1h[SW_CAP];     // 3072 B bf16(s1) per entry
    __shared__ float Ens[512];                 // 2048 B ||e||^2 (this half)
    __shared__ float rminS[256];               // final per-query bf16 half-min
    __shared__ float zzS[256];                 // ||z||^2 for this block
    __shared__ int lcnt;

    const int t = threadIdx.x;
    const int w = t >> 6, lane = t & 63;       // 8 waves
    const int col = lane & 15, quad = lane >> 4;
    const int qb   = blockIdx.x & 255;
    const int half = blockIdx.x >> 8;
    const int qbase = qb * 256;
    const int koff  = half * 512;
    const unsigned short* etH = et + (size_t)half * (512 * 256);

    if (t == 0) lcnt = 0;
    Ens[t] = enorm[koff + t];                  // 512 threads cover 512 codes

    // stage chunk 0 of this half
    {
        const unsigned short* src = etH + w * 2048 + lane * 8;
        unsigned short* dst = &Eb[0][w * 2048];
        #pragma unroll
        for (int i = 0; i < 4; ++i) gll16(src + i * 512, dst + i * 512);
    }

    // A fragments (2 tiles of 16 queries) direct from global z + fused ||z||^2
    bf16x8 A[2][8];
    #pragma unroll
    for (int rt = 0; rt < 2; ++rt) {
        float s = 0.f;
        #pragma unroll
        for (int ds = 0; ds < 8; ++ds) {
            const float* zp = &z[(size_t)(qbase + w*32 + rt*16 + col) * D_DIM
                                 + ds*32 + quad*8];
            float4 a = *(const float4*)zp;
            float4 b = *(const float4*)(zp + 4);
            s += a.x*a.x + a.y*a.y + a.z*a.z + a.w*a.w
               + b.x*b.x + b.y*b.y + b.z*b.z + b.w*b.w;
            u16x8 p = pack8(a, b);
            A[rt][ds] = *(bf16x8*)&p;
        }
        s += __shfl_xor(s, 16, 64);
        s += __shfl_xor(s, 32, 64);
        if (quad == 0) {
            if (half == 0) zzg[qbase + w*32 + rt*16 + col] = s;
            zzS[w*32 + rt*16 + col] = s;
        }
    }

    float rmin[2][4];     // running per-query bf16-s1 half-min
    #pragma unroll
    for (int rt = 0; rt < 2; ++rt)
        #pragma unroll
        for (int rg = 0; rg < 4; ++rg) rmin[rt][rg] = FLT_MAX;

    // prologue sync: full drain once (chunk-0 staging + Ens/zzS LDS writes)
    asm volatile("s_waitcnt vmcnt(0) lgkmcnt(0)" ::: "memory");
    __builtin_amdgcn_s_barrier();
    __builtin_amdgcn_sched_barrier(0);

    #pragma unroll 1
    for (int kc = 0; kc < 8; ++kc) {
        // issue next chunk's staging (hides under this chunk's compute)
        if (kc < 7) {
            const unsigned short* src = etH + (kc + 1) * 16384 + w * 2048 + lane * 8;
            unsigned short* dst = &Eb[(kc + 1) & 1][w * 2048];
            #pragma unroll
            for (int i = 0; i < 4; ++i) gll16(src + i * 512, dst + i * 512);
        }

        const unsigned short* buf = Eb[kc & 1];
        f32x4 acc[2][4];
        #pragma unroll
        for (int rt = 0; rt < 2; ++rt)
            #pragma unroll
            for (int ct = 0; ct < 4; ++ct)
                acc[rt][ct] = (f32x4){0.f, 0.f, 0.f, 0.f};

        #pragma unroll
        for (int ds = 0; ds < 8; ++ds) {
            bf16x8 B[4];
            #pragma unroll
            for (int ct = 0; ct < 4; ++ct)
                B[ct] = *(const bf16x8*)&buf[((ct*32 + ds*4 + quad)*16 + col)*8];
            #pragma unroll
            for (int ct = 0; ct < 4; ++ct) {
                acc[0][ct] = __builtin_amdgcn_mfma_f32_16x16x32_bf16(A[0][ds], B[ct], acc[0][ct], 0, 0, 0);
                acc[1][ct] = __builtin_amdgcn_mfma_f32_16x16x32_bf16(A[1][ds], B[ct], acc[1][ct], 0, 0, 0);
            }
        }

        // ---- epilogue per rt tile (limits live registers) ----
        #pragma unroll
        for (int rt = 0; rt < 2; ++rt) {
            float en4[4];
            #pragma unroll
            for (int ct = 0; ct < 4; ++ct) en4[ct] = Ens[kc*64 + ct*16 + col];

            float s1v[4][4];      // [ct][rg], all static indices
            #pragma unroll
            for (int ct = 0; ct < 4; ++ct)
                #pragma unroll
                for (int rg = 0; rg < 4; ++rg)
                    s1v[ct][rg] = fmaf(-2.0f, acc[rt][ct][rg], en4[ct]);

            float m4[4];
            #pragma unroll
            for (int rg = 0; rg < 4; ++rg)
                m4[rg] = fminf(fminf(s1v[0][rg], s1v[1][rg]),
                               fminf(s1v[2][rg], s1v[3][rg]));

            // level-synchronous xor-min across the 16 col-lanes
            #pragma unroll
            for (int i = 0; i < 4; ++i) m4[i] = SWZMIN(m4[i], 0x041F);  // ^1
            #pragma unroll
            for (int i = 0; i < 4; ++i) m4[i] = SWZMIN(m4[i], 0x081F);  // ^2
            #pragma unroll
            for (int i = 0; i < 4; ++i) m4[i] = SWZMIN(m4[i], 0x101F);  // ^4
            #pragma unroll
            for (int i = 0; i < 4; ++i) m4[i] = SWZMIN(m4[i], 0x201F);  // ^8

            float thrv[4];
            #pragma unroll
            for (int i = 0; i < 4; ++i) {
                rmin[rt][i] = fminf(rmin[rt][i], m4[i]);
                thrv[i] = rmin[rt][i] + DELTA;
            }

            #pragma unroll
            for (int rg = 0; rg < 4; ++rg) {
                float th = thrv[rg];
                #pragma unroll
                for (int ct = 0; ct < 4; ++ct) {
                    if (s1v[ct][rg] <= th) {
                        int k    = koff + kc*64 + ct*16 + col;
                        int qloc = w*32 + rt*16 + quad*4 + rg;
                        int pos  = atomicAdd(&lcnt, 1);
                        if (pos < SW_CAP) {
                            list[pos] = ((unsigned)qloc << 10) | (unsigned)k;
                            s1h[pos]  = f2bf(s1v[ct][rg]);
                        } else {
                            int sp = atomicAdd(spc, 1);
                            if (sp < SPILL_CAP)
                                spill[sp] = ((unsigned)(qbase + qloc) << 10)
                                          | (unsigned)k;
                        }
                    }
                }
            }
        }

        // staged loads had a full chunk of compute slack -> drain is ~free,
        // and guarantees the next buffer is complete for ALL waves.
        asm volatile("s_waitcnt vmcnt(0)" ::: "memory");
        __builtin_amdgcn_s_barrier();
        __builtin_amdgcn_sched_barrier(0);
    }

    // publish final per-query half-min for the tail filter
    if (col == 0) {
        #pragma unroll
        for (int rt = 0; rt < 2; ++rt)
            #pragma unroll
            for (int rg = 0; rg < 4; ++rg)
                rminS[w*32 + rt*16 + quad*4 + rg] = rmin[rt][rg];
    }
    asm volatile("s_waitcnt lgkmcnt(0)" ::: "memory");
    __builtin_amdgcn_s_barrier();
    __builtin_amdgcn_sched_barrier(0);

    // exact rescore of candidates: 8-lane group per entry, lane covers 32 d
    int cnt = lcnt; if (cnt > SW_CAP) cnt = SW_CAP;
    int gid = t >> 3, gl = t & 7;          // 64 groups of 8 lanes
    for (int e = gid; e < cnt; e += 64) {
        unsigned ent = list[e];
        int qloc = (int)(ent >> 10), k = (int)(ent & 1023u);
        if (bf2f(s1h[e]) > rminS[qloc] + (DELTA + MARGIN)) continue;
        int qg = qbase + qloc;
        const float* zp  = &z[(size_t)qg * D_DIM + gl * 32];
        const float* epf = &embed[(size_t)k * D_DIM + gl * 32];
        double d0 = 0.0, d1 = 0.0;
        #pragma unroll
        for (int i = 0; i < 4; ++i) {
            float4 a  = *(const float4*)&zp[i*8];
            float4 b  = *(const float4*)&epf[i*8];
            float4 c  = *(const float4*)&zp[i*8 + 4];
            float4 dv = *(const float4*)&epf[i*8 + 4];
            d0 += (double)a.x*b.x + (double)a.y*b.y + (double)a.z*b.z + (double)a.w*b.w;
            d1 += (double)c.x*dv.x + (double)c.y*dv.y + (double)c.z*dv.z + (double)c.w*dv.w;
        }
        double dd = d0 + d1;
        #pragma unroll
        for (int m = 1; m < 8; m <<= 1) dd += __shfl_xor(dd, m, 64);
        if (gl == 0) {
            float s = (zzS[qloc] - 2.0f*(float)dd) + Ens[k & 511];  // ref op order
            unsigned long long pk =
                ((unsigned long long)__float_as_uint(s) << 32) | (unsigned)k;
            atomicMin(&pack[qg], pk);
        }
    }
}

// ---------------------------------------------------------------------------
// drain the spill pool (normally empty): exact rescore of overflow entries
__global__ void spill_kernel(const float* __restrict__ z,
                             const float* __restrict__ embed,
                             const float* __restrict__ enorm,
                             const float* __restrict__ zz,
                             const unsigned* __restrict__ spill,
                             const int* __restrict__ spc,
                             unsigned long long* __restrict__ pack)
{
    int cnt = *spc; if (cnt > SPILL_CAP) cnt = SPILL_CAP;
    int gid = (blockIdx.x * 256 + threadIdx.x) >> 3, gl = threadIdx.x & 7;
    int stride = (gridDim.x * 256) >> 3;
    for (int e = gid; e < cnt; e += stride) {
        unsigned ent = spill[e];
        int qg = (int)(ent >> 10), k = (int)(ent & 1023u);
        const float* zp  = &z[(size_t)qg * D_DIM + gl * 32];
        const float* epf = &embed[(size_t)k * D_DIM + gl * 32];
        double dd = 0.0;
        #pragma unroll
        for (int i = 0; i < 8; ++i) {
            float4 a = *(const float4*)&zp[i*4];
            float4 b = *(const float4*)&epf[i*4];
            dd += (double)a.x*b.x + (double)a.y*b.y
                + (double)a.z*b.z + (double)a.w*b.w;
        }
        #pragma unroll
        for (int m = 1; m < 8; m <<= 1) dd += __shfl_xor(dd, m, 64);
        if (gl == 0) {
            float s = (zz[qg] - 2.0f*(float)dd) + enorm[k];
            unsigned long long pk =
                ((unsigned long long)__float_as_uint(s) << 32) | (unsigned)k;
            atomicMin(&pack[qg], pk);
        }
    }
}

// ---------------------------------------------------------------------------
// merged unpack + q_st + loss: per block 4 queries x 256 d. Thread t<4 reads
// pack, writes idx (int+float), histograms icnt; all threads gather q, write
// q_st, accumulate sum((z-q)^2) into 1024 double buckets.
__global__ void qst_unpack_kernel(const unsigned long long* __restrict__ pack,
                                  const float* __restrict__ z,
                                  const float* __restrict__ embed,
                                  int* __restrict__ idx_i,
                                  float* __restrict__ idx_f,
                                  int* __restrict__ icnt,
                                  float* __restrict__ qst,
                                  double* __restrict__ lossb)
{
    __shared__ int ks[4];
    int b = blockIdx.x, t = threadIdx.x;
    int n0 = b * 4;
    if (t < 4) {
        int k = (int)(pack[n0 + t] & 0xffffffffull);
        ks[t] = k;
        idx_i[n0 + t] = k;
        idx_f[n0 + t] = (float)k;
        atomicAdd(&icnt[k], 1);
    }
    __syncthreads();
    int e0 = b * 1024 + t * 4;
    int qi = t >> 6;                   // query within block
    int d  = (t * 4) & 255;
    int k  = ks[qi];
    const float4 q4 = *(const float4*)&embed[(size_t)k * D_DIM + d];
    const float4 z4 = *(const float4*)&z[e0];
    float4 o;
    o.x = z4.x + (q4.x - z4.x);
    o.y = z4.y + (q4.y - z4.y);
    o.z = z4.z + (q4.z - z4.z);
    o.w = z4.w + (q4.w - z4.w);
    *(float4*)&qst[e0] = o;
    float dx = z4.x - q4.x, dy = z4.y - q4.y, dz = z4.z - q4.z, dw = z4.w - q4.w;
    float s = dx * dx + dy * dy + dz * dz + dw * dw;
    #pragma unroll
    for (int m = 32; m >= 1; m >>= 1) s += __shfl_down(s, m, 64);
    __shared__ float ps[4];
    int wave = t >> 6, lane = t & 63;
    if (lane == 0) ps[wave] = s;
    __syncthreads();
    if (t == 0)
        atomicAdd(&lossb[b & 1023],
                  (double)((ps[0] + ps[1]) + (ps[2] + ps[3])));
}

// ---------------------------------------------------------------------------
// exclusive scan of counts (1 block x 1024) -> offsets + fill cursor + float counts
__global__ void scan_kernel(const int* __restrict__ icnt,
                            int* __restrict__ offs,
                            int* __restrict__ offw,
                            float* __restrict__ cntf)
{
    __shared__ int s[1024];
    int t = threadIdx.x;
    int v0 = icnt[t];
    s[t] = v0;
    __syncthreads();
    for (int d = 1; d < 1024; d <<= 1) {
        int v = (t >= d) ? s[t - d] : 0;
        __syncthreads();
        s[t] += v;
        __syncthreads();
    }
    int excl = s[t] - v0;
    offs[t] = excl;
    offw[t] = excl;
    cntf[t] = (float)v0;
}

// ---------------------------------------------------------------------------
// build CSR permutation (order within a code arbitrary; accum uses double)
__global__ void fill_kernel(const int* __restrict__ idx,
                            int* __restrict__ offw,
                            int* __restrict__ perm)
{
    int n = blockIdx.x * 256 + threadIdx.x;
    int k = idx[n];
    int pos = atomicAdd(&offw[k], 1);
    perm[pos] = n;
}

// ---------------------------------------------------------------------------
// new_count, n = sum(new_count), cs, vq_loss finalize (single block of 1024)
__global__ void fin_counts_kernel(const float* __restrict__ ema_count,
                                  const float* __restrict__ cntf,
                                  const double* __restrict__ lossb,
                                  float* __restrict__ out_count,
                                  float* __restrict__ out_loss,
                                  float* __restrict__ cs)
{
    __shared__ float  red[1024];
    __shared__ double dred[1024];
    int t = threadIdx.x;
    float c = 0.99f * ema_count[t] + 0.01f * cntf[t];
    out_count[t] = c;
    red[t]  = c;
    dred[t] = lossb[t];
    __syncthreads();
    for (int s = 512; s >= 1; s >>= 1) {
        if (t < s) { red[t] += red[t + s]; dred[t] += dred[t + s]; }
        __syncthreads();
    }
    float n = red[0];
    cs[t] = (c + 1e-5f) / (n + 1024.0f * 1e-5f) * n;
    if (t == 0) {
        float m = (float)(dred[0] / (double)((size_t)N_Q * D_DIM));
        out_loss[0] = m + 0.25f * m;   // codebook + BETA*commit, bitwise equal halves
    }
}

// ---------------------------------------------------------------------------
// per-code: dw[k,d] = sum over members of z (double accum, 4-way ILP), then
// EMA + normalize. One block per code; thread t handles column d=t.
__global__ void accum_embed_kernel(const float* __restrict__ z,
                                   const int* __restrict__ perm,
                                   const int* __restrict__ icnt,
                                   const int* __restrict__ offs,
                                   const float* __restrict__ cs,
                                   const float* __restrict__ ema_w,
                                   float* __restrict__ out_embed,
                                   float* __restrict__ out_emaw)
{
    __shared__ int rows[256];
    int k = blockIdx.x, t = threadIdx.x;
    int cnt = icnt[k], off = offs[k];
    double a0 = 0.0, a1 = 0.0, a2 = 0.0, a3 = 0.0;
    for (int base = 0; base < cnt; base += 256) {
        int m = min(256, cnt - base);
        __syncthreads();
        if (t < m) rows[t] = perm[off + base + t];
        __syncthreads();
        int r = 0;
        for (; r + 4 <= m; r += 4) {
            a0 += (double)z[(size_t)rows[r+0] * D_DIM + t];
            a1 += (double)z[(size_t)rows[r+1] * D_DIM + t];
            a2 += (double)z[(size_t)rows[r+2] * D_DIM + t];
            a3 += (double)z[(size_t)rows[r+3] * D_DIM + t];
        }
        for (; r < m; ++r) a0 += (double)z[(size_t)rows[r] * D_DIM + t];
    }
    double acc = (a0 + a1) + (a2 + a3);
    float w = 0.99f * ema_w[(size_t)k * D_DIM + t] + 0.01f * (float)acc;
    out_emaw[(size_t)k * D_DIM + t]  = w;
    out_embed[(size_t)k * D_DIM + t] = w / cs[k];
}

// ---------------------------------------------------------------------------
extern "C" void kernel_launch(void* const* d_in, const int* in_sizes, int n_in,
                              void* d_out, int out_size, void* d_ws, size_t ws_size,
                              hipStream_t stream)
{
    const float* z          = (const float*)d_in[0];
    const float* embed      = (const float*)d_in[1];
    const float* ema_count  = (const float*)d_in[2];
    const float* ema_weight = (const float*)d_in[3];
    float* out = (float*)d_out;
    char*  ws  = (char*)d_ws;

    int*      ws_idx  = (int*)(ws + WS_IDX);
    unsigned* ws_spill= (unsigned*)(ws + WS_IDX);   // aliased: free during sweep
    float*    ws_zz   = (float*)(ws + WS_ZZ);
    int*      ws_perm = (int*)(ws + WS_PERM);
    unsigned long long* ws_pack = (unsigned long long*)(ws + WS_PACK);
    float*    ws_en   = (float*)(ws + WS_EN);
    int*      ws_icnt = (int*)(ws + WS_ICNT);
    int*      ws_offs = (int*)(ws + WS_OFFS);
    int*      ws_offw = (int*)(ws + WS_OFFW);
    float*    ws_cntf = (float*)(ws + WS_CNTF);
    float*    ws_cs   = (float*)(ws + WS_CS);
    unsigned short* ws_et = (unsigned short*)(ws + WS_ET);
    double*   ws_lb   = (double*)(ws + WS_LOSSB);
    int*      ws_spc  = (int*)(ws + WS_SPCNT);

    prep_kernel<<<160, 256, 0, stream>>>(embed, ws_et, ws_pack, ws_en,
                                         ws_icnt, ws_lb, ws_spc);

    sweep_kernel<<<512, 512, 0, stream>>>(z, embed, ws_et, ws_en, ws_zz,
                                          ws_pack, ws_spill, ws_spc);

    spill_kernel<<<32, 256, 0, stream>>>(z, embed, ws_en, ws_zz,
                                         ws_spill, ws_spc, ws_pack);

    qst_unpack_kernel<<<N_Q / 4, 256, 0, stream>>>(ws_pack, z, embed,
                                                   ws_idx, out + OUT_IDX,
                                                   ws_icnt, out + OUT_QST, ws_lb);
    scan_kernel<<<1, 1024, 0, stream>>>(ws_icnt, ws_offs, ws_offw, ws_cntf);
    fill_kernel<<<N_Q / 256, 256, 0, stream>>>(ws_idx, ws_offw, ws_perm);
    fin_counts_kernel<<<1, 1024, 0, stream>>>(ema_count, ws_cntf, ws_lb,
                                              out + OUT_COUNT, out + OUT_LOSS, ws_cs);
    accum_embed_kernel<<<K_CODES, 256, 0, stream>>>(z, ws_perm, ws_icnt, ws_offs,
                                                    ws_cs, ema_weight,
                                                    out + OUT_EMBED, out + OUT_EMAW);
}

// Round 7
// 271.394 us; speedup vs baseline: 1.3156x; 1.3156x over previous
//
#include <hip/hip_runtime.h>
#include <cfloat>

#define N_Q     65536
#define D_DIM   256
#define K_CODES 1024
#define DELTA   0.004f
#define MARGIN  0.001f
#define SW_CAP  1536
#define SPILL_CAP 65536

// output float offsets (tuple concatenated flat, all as float32)
#define OUT_QST   0
#define OUT_LOSS  16777216
#define OUT_IDX   16777217
#define OUT_EMBED 16842753
#define OUT_COUNT 17104897
#define OUT_EMAW  17105921

// workspace byte offsets
#define WS_IDX    0u         // 65536*4: spill pool during sweep, idx after
#define WS_ZZ     262144u    // 65536*4 float ||z||^2 (written by sweep prologue)
#define WS_PERM   524288u    // 65536*4 int CSR permutation
#define WS_PACK   786432u    // 65536*8 uint64 packed (dist,idx), init by prep
#define WS_EN     1310720u   // 1024*4 float ||e||^2
#define WS_ICNT   1314816u   // 1024*4 int counts, zeroed by prep
#define WS_OFFS   1318912u   // 1024*4 int CSR offsets
#define WS_OFFW   1323008u   // 1024*4 int CSR fill cursor
#define WS_CNTF   1327104u   // 1024*4 float counts
#define WS_CS     1331200u   // 1024*4 float laplace-smoothed counts
#define WS_ET     1335296u   // 1024*256*2 bf16 embed in B-fragment layout
#define WS_LOSSB  1859584u   // 1024*8 double loss buckets, zeroed by prep
#define WS_SPCNT  1867776u   // 4 B spill counter, zeroed by prep

typedef short          bf16x8 __attribute__((ext_vector_type(8)));
typedef unsigned short u16x8  __attribute__((ext_vector_type(8)));
typedef float          f32x4  __attribute__((ext_vector_type(4)));

__device__ inline unsigned short f2bf(float x) {   // RNE fp32 -> bf16
    unsigned u = __float_as_uint(x);
    u += 0x7FFFu + ((u >> 16) & 1u);
    return (unsigned short)(u >> 16);
}
__device__ inline float bf2f(unsigned short h) {
    return __uint_as_float((unsigned)h << 16);
}
__device__ inline u16x8 pack8(float4 a, float4 b) {
    u16x8 p;
    p[0]=f2bf(a.x); p[1]=f2bf(a.y); p[2]=f2bf(a.z); p[3]=f2bf(a.w);
    p[4]=f2bf(b.x); p[5]=f2bf(b.y); p[6]=f2bf(b.z); p[7]=f2bf(b.w);
    return p;
}
// async global->LDS, 16B per lane; lds dest is wave-uniform base + lane*16
__device__ inline void gll16(const void* g, void* l) {
    __builtin_amdgcn_global_load_lds(
        (const __attribute__((address_space(1))) unsigned int*)g,
        (__attribute__((address_space(3))) unsigned int*)l, 16, 0, 0);
}
// min with a DPP lane-permuted partner (VALU pipe, not LDS).
//   0xB1 = quad_perm [1,0,3,2] (xor1), 0x4E = quad_perm [2,3,0,1] (xor2),
//   0x124 = row_ror:4, 0x128 = row_ror:8 (rows = 16 lanes on gfx9/CDNA).
// Fail-safe: row-confined permutes only ever mix lanes of the SAME query's
// code slots, so any outcome is a min over a subset => threshold >= true
// threshold => push set stays a superset (correctness preserved).
#define DPPMIN(x, CTRL) fminf((x), __int_as_float( \
    __builtin_amdgcn_update_dpp(0, __float_as_int(x), (CTRL), 0xF, 0xF, false)))

// ---------------------------------------------------------------------------
// fused prep: conv_e + pack init (blocks 0..127), ||e||^2 + counter zeroing
// (blocks 128..159).
__global__ void prep_kernel(const float* __restrict__ embed,
                            unsigned short* __restrict__ et,
                            unsigned long long* __restrict__ pack,
                            float* __restrict__ enorm,
                            int* __restrict__ icnt,
                            double* __restrict__ lossb,
                            int* __restrict__ spc)
{
    int b = blockIdx.x, t = threadIdx.x;
    if (b < 128) {
        int tid = b * 256 + t;                        // 32768 threads
        // embed fp32 -> bf16 in MFMA B-fragment layout:
        //   et[((k16*32 + d8)*16 + col)*8 + j] = bf16(e[k16*16+col][d8*8+j])
        int k16 = tid >> 9, d8 = (tid >> 4) & 31, col = tid & 15;
        const float* src = &embed[(size_t)(k16 * 16 + col) * D_DIM + d8 * 8];
        float4 a = *(const float4*)&src[0];
        float4 c = *(const float4*)&src[4];
        *(u16x8*)&et[(size_t)tid * 8] = pack8(a, c);
        // pack init (0xFF..): 16 B per thread covers 65536*8 B
        unsigned long long* p = pack + (size_t)tid * 2;
        p[0] = ~0ull; p[1] = ~0ull;
    } else {
        int b2 = b - 128;                             // 0..31
        int wave = t >> 6, lane = t & 63;
        int rbase = (b2 * 4 + wave) * 8;              // 8 rows per wave
        for (int i = 0; i < 8; ++i) {
            int r = rbase + i;
            const float4 v = *(const float4*)&embed[(size_t)r * D_DIM + lane * 4];
            float s = v.x * v.x + v.y * v.y + v.z * v.z + v.w * v.w;
            #pragma unroll
            for (int m = 32; m >= 1; m >>= 1) s += __shfl_down(s, m, 64);
            if (lane == 0) enorm[r] = s;
        }
        if (b2 == 0) {
            #pragma unroll
            for (int i = 0; i < 4; ++i) {
                icnt[t * 4 + i] = 0;
                lossb[t * 4 + i] = 0.0;
            }
            if (t == 0) *spc = 0;
        }
    }
}

// ---------------------------------------------------------------------------
// Single merged MFMA sweep, counted-vmcnt pipeline (T3+T4, m201 pattern).
// Structure identical to the round-4 kernel that passed at 111.6 us; the only
// change is the epilogue min-reduce: ds_swizzle (LDS pipe) -> DPP (VALU pipe).
//   - 512 threads (8 waves), 16 queries/wave, 512 blocks -> 2 blocks/CU,
//     16 waves/CU (4/SIMD).
//   - per 64-code chunk: issue next chunk's 32 KB et staging (4 gll16/wave,
//     double-buffered), compute current from LDS (32 ds_read_b128 + 32 MFMA
//     per wave), epilogue (DPP min-reduce + running-min pushes), then
//     s_waitcnt vmcnt(4) + raw s_barrier + sched_barrier(0): counted wait
//     leaves next-chunk loads in flight across the barrier.
//   - A fragments built once from global z; fused ||z||^2.
//   - tail: re-filter candidates vs FINAL min+DELTA+MARGIN, exact double
//     rescore, ref op order fl(fl(zz-2dot)+en), first-index ties via packed
//     u64 atomicMin on pack[].
// Layouts (verified, guide §3): A[m=lane&15][k=quad*8+j]; C/D col=lane&15,
// row=quad*4+reg. B loaded from E rows (B^T convention, m91).
__launch_bounds__(512, 4)
__global__ void sweep_kernel(const float* __restrict__ z,
                             const float* __restrict__ embed,
                             const unsigned short* __restrict__ et,
                             const float* __restrict__ enorm,
                             float* __restrict__ zzg,
                             unsigned long long* __restrict__ pack,
                             unsigned* __restrict__ spill,
                             int* __restrict__ spc)
{
    __shared__ unsigned short Eb[2][16384];    // 2 x 32 KB E chunk double buffer
    __shared__ unsigned list[SW_CAP];          // 6144 B candidate entries
    __shared__ unsigned short s1h[SW_CAP];     // 3072 B bf16(s1) per entry
    __shared__ float Ens[K_CODES];             // 4096 B ||e||^2
    __shared__ float rminS[128];               // final per-query bf16 min
    __shared__ float zzS[128];                 // ||z||^2 for this block
    __shared__ int lcnt;

    const int t = threadIdx.x;
    const int w = t >> 6, lane = t & 63;       // 8 waves
    const int col = lane & 15, quad = lane >> 4;
    const int qbase = blockIdx.x * 128;

    if (t == 0) lcnt = 0;
    for (int i = t; i < K_CODES; i += 512) Ens[i] = enorm[i];

    // stage chunk 0: wave w covers shorts [w*2048, +2048) of the 16384-short chunk
    {
        const unsigned short* src = et + w * 2048 + lane * 8;
        unsigned short* dst = &Eb[0][w * 2048];
        #pragma unroll
        for (int i = 0; i < 4; ++i) gll16(src + i * 512, dst + i * 512);
    }

    // A fragments direct from global z + fused ||z||^2.
    // wave w owns queries qbase + w*16 + [0,16); lane(col,quad) covers row
    // (w*16+col), dims {ds*32+quad*8..+8}; quad lanes partition the row.
    bf16x8 A[8];
    {
        float s = 0.f;
        #pragma unroll
        for (int ds = 0; ds < 8; ++ds) {
            const float* zp = &z[(size_t)(qbase + w*16 + col) * D_DIM
                                 + ds*32 + quad*8];
            float4 a = *(const float4*)zp;
            float4 b = *(const float4*)(zp + 4);
            s += a.x*a.x + a.y*a.y + a.z*a.z + a.w*a.w
               + b.x*b.x + b.y*b.y + b.z*b.z + b.w*b.w;
            u16x8 p = pack8(a, b);
            A[ds] = *(bf16x8*)&p;
        }
        s += __shfl_xor(s, 16, 64);
        s += __shfl_xor(s, 32, 64);
        if (quad == 0) {
            zzg[qbase + w*16 + col] = s;
            zzS[w*16 + col] = s;
        }
    }

    float rmin[4];        // running per-query bf16-s1 min (uniform across col)
    #pragma unroll
    for (int i = 0; i < 4; ++i) rmin[i] = FLT_MAX;

    // prologue sync: full drain once (chunk-0 staging + Ens/zzS LDS writes)
    asm volatile("s_waitcnt vmcnt(0) lgkmcnt(0)" ::: "memory");
    __builtin_amdgcn_s_barrier();
    __builtin_amdgcn_sched_barrier(0);

    #pragma unroll 1
    for (int kc = 0; kc < 16; ++kc) {
        // issue next chunk's staging (stays in flight across the barrier)
        if (kc < 15) {
            const unsigned short* src = et + (kc + 1) * 16384 + w * 2048 + lane * 8;
            unsigned short* dst = &Eb[(kc + 1) & 1][w * 2048];
            #pragma unroll
            for (int i = 0; i < 4; ++i) gll16(src + i * 512, dst + i * 512);
        }

        const unsigned short* buf = Eb[kc & 1];
        f32x4 acc[4];
        #pragma unroll
        for (int ct = 0; ct < 4; ++ct)
            acc[ct] = (f32x4){0.f, 0.f, 0.f, 0.f};

        #pragma unroll
        for (int ds = 0; ds < 8; ++ds) {
            bf16x8 B[4];
            #pragma unroll
            for (int ct = 0; ct < 4; ++ct)
                B[ct] = *(const bf16x8*)&buf[((ct*32 + ds*4 + quad)*16 + col)*8];
            #pragma unroll
            for (int ct = 0; ct < 4; ++ct)
                acc[ct] = __builtin_amdgcn_mfma_f32_16x16x32_bf16(A[ds], B[ct], acc[ct], 0, 0, 0);
        }

        // ---- epilogue: straight-line s1, DPP min-reduce, compact push ----
        float en4[4];
        #pragma unroll
        for (int ct = 0; ct < 4; ++ct) en4[ct] = Ens[kc*64 + ct*16 + col];

        float s1v[4][4];      // [ct][rg], all static indices
        #pragma unroll
        for (int ct = 0; ct < 4; ++ct)
            #pragma unroll
            for (int rg = 0; rg < 4; ++rg)
                s1v[ct][rg] = fmaf(-2.0f, acc[ct][rg], en4[ct]);

        float m4[4];          // per-lane min over ct, per rg
        #pragma unroll
        for (int rg = 0; rg < 4; ++rg)
            m4[rg] = fminf(fminf(s1v[0][rg], s1v[1][rg]),
                           fminf(s1v[2][rg], s1v[3][rg]));

        // 16-col-lane min via DPP (VALU pipe): xor1, xor2 within quads, then
        // ror4 + ror8 across the quads of the 16-lane row. Covers all 16.
        #pragma unroll
        for (int i = 0; i < 4; ++i) m4[i] = DPPMIN(m4[i], 0xB1);   // xor1
        #pragma unroll
        for (int i = 0; i < 4; ++i) m4[i] = DPPMIN(m4[i], 0x4E);   // xor2
        #pragma unroll
        for (int i = 0; i < 4; ++i) m4[i] = DPPMIN(m4[i], 0x124);  // ror:4
        #pragma unroll
        for (int i = 0; i < 4; ++i) m4[i] = DPPMIN(m4[i], 0x128);  // ror:8

        float thrv[4];
        #pragma unroll
        for (int i = 0; i < 4; ++i) {
            rmin[i] = fminf(rmin[i], m4[i]);
            thrv[i] = rmin[i] + DELTA;
        }

        #pragma unroll
        for (int rg = 0; rg < 4; ++rg) {
            float th = thrv[rg];
            #pragma unroll
            for (int ct = 0; ct < 4; ++ct) {
                if (s1v[ct][rg] <= th) {
                    int k    = kc*64 + ct*16 + col;
                    int qloc = w*16 + quad*4 + rg;
                    int pos  = atomicAdd(&lcnt, 1);
                    if (pos < SW_CAP) {
                        list[pos] = ((unsigned)qloc << 10) | (unsigned)k;
                        s1h[pos]  = f2bf(s1v[ct][rg]);
                    } else {
                        int sp = atomicAdd(spc, 1);
                        if (sp < SPILL_CAP) {
                            spill[sp] = ((unsigned)(qbase + qloc) << 10)
                                      | (unsigned)k;
                            // rare: drain so stores never pollute the
                            // counted vmcnt(4) below
                            asm volatile("s_waitcnt vmcnt(0)" ::: "memory");
                        }
                    }
                }
            }
        }

        // counted wait: only the 4 newest ops (next chunk's staging) may
        // remain in flight; then rendezvous. NO vmcnt(0) drain in-loop.
        asm volatile("s_waitcnt vmcnt(4)" ::: "memory");
        __builtin_amdgcn_s_barrier();
        __builtin_amdgcn_sched_barrier(0);
    }

    // publish final per-query min for the tail filter
    if (col == 0) {
        #pragma unroll
        for (int rg = 0; rg < 4; ++rg)
            rminS[w*16 + quad*4 + rg] = rmin[rg];
    }
    asm volatile("s_waitcnt lgkmcnt(0)" ::: "memory");
    __builtin_amdgcn_s_barrier();
    __builtin_amdgcn_sched_barrier(0);
    asm volatile("" ::: "memory");

    // exact rescore of candidates: 8-lane group per entry, lane covers 32 d;
    // skip entries whose stored bf16(s1) exceeds FINAL min + DELTA (+MARGIN)
    int cnt = lcnt; if (cnt > SW_CAP) cnt = SW_CAP;
    int gid = t >> 3, gl = t & 7;          // 64 groups of 8 lanes
    for (int e = gid; e < cnt; e += 64) {
        unsigned ent = list[e];
        int qloc = (int)(ent >> 10), k = (int)(ent & 1023u);
        if (bf2f(s1h[e]) > rminS[qloc] + (DELTA + MARGIN)) continue;
        int qg = qbase + qloc;
        const float* zp  = &z[(size_t)qg * D_DIM + gl * 32];
        const float* epf = &embed[(size_t)k * D_DIM + gl * 32];
        double d0 = 0.0, d1 = 0.0;
        #pragma unroll
        for (int i = 0; i < 4; ++i) {
            float4 a  = *(const float4*)&zp[i*8];
            float4 b  = *(const float4*)&epf[i*8];
            float4 c  = *(const float4*)&zp[i*8 + 4];
            float4 dv = *(const float4*)&epf[i*8 + 4];
            d0 += (double)a.x*b.x + (double)a.y*b.y + (double)a.z*b.z + (double)a.w*b.w;
            d1 += (double)c.x*dv.x + (double)c.y*dv.y + (double)c.z*dv.z + (double)c.w*dv.w;
        }
        double dd = d0 + d1;
        #pragma unroll
        for (int m = 1; m < 8; m <<= 1) dd += __shfl_xor(dd, m, 64);
        if (gl == 0) {
            float s = (zzS[qloc] - 2.0f*(float)dd) + Ens[k];  // ref op order
            unsigned long long pk =
                ((unsigned long long)__float_as_uint(s) << 32) | (unsigned)k;
            atomicMin(&pack[qg], pk);
        }
    }
}

// ---------------------------------------------------------------------------
// drain the spill pool (normally empty): exact rescore of overflow entries
__global__ void spill_kernel(const float* __restrict__ z,
                             const float* __restrict__ embed,
                             const float* __restrict__ enorm,
                             const float* __restrict__ zz,
                             const unsigned* __restrict__ spill,
                             const int* __restrict__ spc,
                             unsigned long long* __restrict__ pack)
{
    int cnt = *spc; if (cnt > SPILL_CAP) cnt = SPILL_CAP;
    int gid = (blockIdx.x * 256 + threadIdx.x) >> 3, gl = threadIdx.x & 7;
    int stride = (gridDim.x * 256) >> 3;
    for (int e = gid; e < cnt; e += stride) {
        unsigned ent = spill[e];
        int qg = (int)(ent >> 10), k = (int)(ent & 1023u);
        const float* zp  = &z[(size_t)qg * D_DIM + gl * 32];
        const float* epf = &embed[(size_t)k * D_DIM + gl * 32];
        double dd = 0.0;
        #pragma unroll
        for (int i = 0; i < 8; ++i) {
            float4 a = *(const float4*)&zp[i*4];
            float4 b = *(const float4*)&epf[i*4];
            dd += (double)a.x*b.x + (double)a.y*b.y
                + (double)a.z*b.z + (double)a.w*b.w;
        }
        #pragma unroll
        for (int m = 1; m < 8; m <<= 1) dd += __shfl_xor(dd, m, 64);
        if (gl == 0) {
            float s = (zz[qg] - 2.0f*(float)dd) + enorm[k];
            unsigned long long pk =
                ((unsigned long long)__float_as_uint(s) << 32) | (unsigned)k;
            atomicMin(&pack[qg], pk);
        }
    }
}

// ---------------------------------------------------------------------------
// merged unpack + q_st + loss: per block 4 queries x 256 d. Thread t<4 reads
// pack, writes idx (int+float), histograms icnt; all threads gather q, write
// q_st, accumulate sum((z-q)^2) into 1024 double buckets. (validated in r5)
__global__ void qst_unpack_kernel(const unsigned long long* __restrict__ pack,
                                  const float* __restrict__ z,
                                  const float* __restrict__ embed,
                                  int* __restrict__ idx_i,
                                  float* __restrict__ idx_f,
                                  int* __restrict__ icnt,
                                  float* __restrict__ qst,
                                  double* __restrict__ lossb)
{
    __shared__ int ks[4];
    int b = blockIdx.x, t = threadIdx.x;
    int n0 = b * 4;
    if (t < 4) {
        int k = (int)(pack[n0 + t] & 0xffffffffull);
        ks[t] = k;
        idx_i[n0 + t] = k;
        idx_f[n0 + t] = (float)k;
        atomicAdd(&icnt[k], 1);
    }
    __syncthreads();
    int e0 = b * 1024 + t * 4;
    int qi = t >> 6;                   // query within block
    int d  = (t * 4) & 255;
    int k  = ks[qi];
    const float4 q4 = *(const float4*)&embed[(size_t)k * D_DIM + d];
    const float4 z4 = *(const float4*)&z[e0];
    float4 o;
    o.x = z4.x + (q4.x - z4.x);
    o.y = z4.y + (q4.y - z4.y);
    o.z = z4.z + (q4.z - z4.z);
    o.w = z4.w + (q4.w - z4.w);
    *(float4*)&qst[e0] = o;
    float dx = z4.x - q4.x, dy = z4.y - q4.y, dz = z4.z - q4.z, dw = z4.w - q4.w;
    float s = dx * dx + dy * dy + dz * dz + dw * dw;
    #pragma unroll
    for (int m = 32; m >= 1; m >>= 1) s += __shfl_down(s, m, 64);
    __shared__ float ps[4];
    int wave = t >> 6, lane = t & 63;
    if (lane == 0) ps[wave] = s;
    __syncthreads();
    if (t == 0)
        atomicAdd(&lossb[b & 1023],
                  (double)((ps[0] + ps[1]) + (ps[2] + ps[3])));
}

// ---------------------------------------------------------------------------
// exclusive scan of counts (1 block x 1024) -> offsets + fill cursor + float counts
__global__ void scan_kernel(const int* __restrict__ icnt,
                            int* __restrict__ offs,
                            int* __restrict__ offw,
                            float* __restrict__ cntf)
{
    __shared__ int s[1024];
    int t = threadIdx.x;
    int v0 = icnt[t];
    s[t] = v0;
    __syncthreads();
    for (int d = 1; d < 1024; d <<= 1) {
        int v = (t >= d) ? s[t - d] : 0;
        __syncthreads();
        s[t] += v;
        __syncthreads();
    }
    int excl = s[t] - v0;
    offs[t] = excl;
    offw[t] = excl;
    cntf[t] = (float)v0;
}

// ---------------------------------------------------------------------------
// build CSR permutation (order within a code arbitrary; accum uses double)
__global__ void fill_kernel(const int* __restrict__ idx,
                            int* __restrict__ offw,
                            int* __restrict__ perm)
{
    int n = blockIdx.x * 256 + threadIdx.x;
    int k = idx[n];
    int pos = atomicAdd(&offw[k], 1);
    perm[pos] = n;
}

// ---------------------------------------------------------------------------
// new_count, n = sum(new_count), cs, vq_loss finalize (single block of 1024)
__global__ void fin_counts_kernel(const float* __restrict__ ema_count,
                                  const float* __restrict__ cntf,
                                  const double* __restrict__ lossb,
                                  float* __restrict__ out_count,
                                  float* __restrict__ out_loss,
                                  float* __restrict__ cs)
{
    __shared__ float  red[1024];
    __shared__ double dred[1024];
    int t = threadIdx.x;
    float c = 0.99f * ema_count[t] + 0.01f * cntf[t];
    out_count[t] = c;
    red[t]  = c;
    dred[t] = lossb[t];
    __syncthreads();
    for (int s = 512; s >= 1; s >>= 1) {
        if (t < s) { red[t] += red[t + s]; dred[t] += dred[t + s]; }
        __syncthreads();
    }
    float n = red[0];
    cs[t] = (c + 1e-5f) / (n + 1024.0f * 1e-5f) * n;
    if (t == 0) {
        float m = (float)(dred[0] / (double)((size_t)N_Q * D_DIM));
        out_loss[0] = m + 0.25f * m;   // codebook + BETA*commit, bitwise equal halves
    }
}

// ---------------------------------------------------------------------------
// per-code: dw[k,d] = sum over members of z (double accum, 4-way ILP), then
// EMA + normalize. One block per code; thread t handles column d=t.
__global__ void accum_embed_kernel(const float* __restrict__ z,
                                   const int* __restrict__ perm,
                                   const int* __restrict__ icnt,
                                   const int* __restrict__ offs,
                                   const float* __restrict__ cs,
                                   const float* __restrict__ ema_w,
                                   float* __restrict__ out_embed,
                                   float* __restrict__ out_emaw)
{
    __shared__ int rows[256];
    int k = blockIdx.x, t = threadIdx.x;
    int cnt = icnt[k], off = offs[k];
    double a0 = 0.0, a1 = 0.0, a2 = 0.0, a3 = 0.0;
    for (int base = 0; base < cnt; base += 256) {
        int m = min(256, cnt - base);
        __syncthreads();
        if (t < m) rows[t] = perm[off + base + t];
        __syncthreads();
        int r = 0;
        for (; r + 4 <= m; r += 4) {
            a0 += (double)z[(size_t)rows[r+0] * D_DIM + t];
            a1 += (double)z[(size_t)rows[r+1] * D_DIM + t];
            a2 += (double)z[(size_t)rows[r+2] * D_DIM + t];
            a3 += (double)z[(size_t)rows[r+3] * D_DIM + t];
        }
        for (; r < m; ++r) a0 += (double)z[(size_t)rows[r] * D_DIM + t];
    }
    double acc = (a0 + a1) + (a2 + a3);
    float w = 0.99f * ema_w[(size_t)k * D_DIM + t] + 0.01f * (float)acc;
    out_emaw[(size_t)k * D_DIM + t]  = w;
    out_embed[(size_t)k * D_DIM + t] = w / cs[k];
}

// ---------------------------------------------------------------------------
extern "C" void kernel_launch(void* const* d_in, const int* in_sizes, int n_in,
                              void* d_out, int out_size, void* d_ws, size_t ws_size,
                              hipStream_t stream)
{
    const float* z          = (const float*)d_in[0];
    const float* embed      = (const float*)d_in[1];
    const float* ema_count  = (const float*)d_in[2];
    const float* ema_weight = (const float*)d_in[3];
    float* out = (float*)d_out;
    char*  ws  = (char*)d_ws;

    int*      ws_idx  = (int*)(ws + WS_IDX);
    unsigned* ws_spill= (unsigned*)(ws + WS_IDX);   // aliased: free during sweep
    float*    ws_zz   = (float*)(ws + WS_ZZ);
    int*      ws_perm = (int*)(ws + WS_PERM);
    unsigned long long* ws_pack = (unsigned long long*)(ws + WS_PACK);
    float*    ws_en   = (float*)(ws + WS_EN);
    int*      ws_icnt = (int*)(ws + WS_ICNT);
    int*      ws_offs = (int*)(ws + WS_OFFS);
    int*      ws_offw = (int*)(ws + WS_OFFW);
    float*    ws_cntf = (float*)(ws + WS_CNTF);
    float*    ws_cs   = (float*)(ws + WS_CS);
    unsigned short* ws_et = (unsigned short*)(ws + WS_ET);
    double*   ws_lb   = (double*)(ws + WS_LOSSB);
    int*      ws_spc  = (int*)(ws + WS_SPCNT);

    prep_kernel<<<160, 256, 0, stream>>>(embed, ws_et, ws_pack, ws_en,
                                         ws_icnt, ws_lb, ws_spc);

    sweep_kernel<<<N_Q / 128, 512, 0, stream>>>(z, embed, ws_et, ws_en, ws_zz,
                                                ws_pack, ws_spill, ws_spc);

    spill_kernel<<<32, 256, 0, stream>>>(z, embed, ws_en, ws_zz,
                                         ws_spill, ws_spc, ws_pack);

    qst_unpack_kernel<<<N_Q / 4, 256, 0, stream>>>(ws_pack, z, embed,
                                                   ws_idx, out + OUT_IDX,
                                                   ws_icnt, out + OUT_QST, ws_lb);
    scan_kernel<<<1, 1024, 0, stream>>>(ws_icnt, ws_offs, ws_offw, ws_cntf);
    fill_kernel<<<N_Q / 256, 256, 0, stream>>>(ws_idx, ws_offw, ws_perm);
    fin_counts_kernel<<<1, 1024, 0, stream>>>(ema_count, ws_cntf, ws_lb,
                                              out + OUT_COUNT, out + OUT_LOSS, ws_cs);
    accum_embed_kernel<<<K_CODES, 256, 0, stream>>>(z, ws_perm, ws_icnt, ws_offs,
                                                    ws_cs, ema_weight,
                                                    out + OUT_EMBED, out + OUT_EMAW);
}